// Round 1
// baseline (86.149 us; speedup 1.0000x reference)
//
#include <hip/hip_runtime.h>
#include <hip/hip_bf16.h>

#define NB 16
#define NC 256
#define NH 64
#define NW 64

typedef __attribute__((ext_vector_type(8))) short bf16x8;
typedef __attribute__((ext_vector_type(4))) float f32x4;

__device__ __forceinline__ unsigned short f2bf(float f) {
    union { float f; unsigned int u; } v; v.f = f;
    unsigned int u = v.u;
    u += 0x7fffu + ((u >> 16) & 1u);   // round-to-nearest-even
    return (unsigned short)(u >> 16);
}

// swizzled elem index, [rows][256] bf16 tile (row = 512B): 16B-block XOR swizzle
__device__ __forceinline__ int idxT(int row, int col) {
    return row * 256 + ((((col >> 3) ^ (row & 7)) << 3) | (col & 7));
}
// swizzled elem index, [rows][64] bf16 tile (row = 128B)
__device__ __forceinline__ int idxS(int row, int col) {
    return row * 64 + ((((col >> 3) ^ (row & 7)) << 3) | (col & 7));
}

__global__ void conv_weights(const float* __restrict__ wq,
                             const float* __restrict__ wk,
                             const float* __restrict__ wv,
                             unsigned short* __restrict__ wsb) {
    int i = blockIdx.x * 256 + threadIdx.x;   // float4 index, 16384 total
    float4 q = ((const float4*)wq)[i];
    float4 k = ((const float4*)wk)[i];
    float4 v = ((const float4*)wv)[i];
    ushort4 uq = { f2bf(q.x), f2bf(q.y), f2bf(q.z), f2bf(q.w) };
    ushort4 uk = { f2bf(k.x), f2bf(k.y), f2bf(k.z), f2bf(k.w) };
    ushort4 uv = { f2bf(v.x), f2bf(v.y), f2bf(v.z), f2bf(v.w) };
    ((ushort4*)wsb)[i] = uq;
    ((ushort4*)(wsb + 65536))[i] = uk;
    ((ushort4*)(wsb + 131072))[i] = uv;
}

__launch_bounds__(512, 1)
__global__ void mha_fused(const float* __restrict__ a,
                          const unsigned short* __restrict__ wsb,
                          const float* __restrict__ bq,
                          const float* __restrict__ bk,
                          const float* __restrict__ bv,
                          float* __restrict__ out) {
    // 136 KiB LDS: AL/QT(32K) | AT(32K) | KT(32K) | Vs(32K) | ATT(8K)
    __shared__ __align__(16) unsigned short smem[69632];
    unsigned short* AL  = smem;          // stage1: [c][w] bf16, reused as QT
    unsigned short* QT  = smem;          // [w][c] swizzled
    unsigned short* AT  = smem + 16384;  // [w][c] swizzled
    unsigned short* KT  = smem + 32768;  // [x][c] swizzled
    unsigned short* Vs  = smem + 49152;  // [c][x] swizzled
    unsigned short* ATT = smem + 65536;  // [w][x] swizzled

    const int tid = threadIdx.x;
    const int b = blockIdx.x >> 6;
    const int h = blockIdx.x & 63;
    const float* aB = a + (size_t)b * (NC * NH * NW) + h * NW;

    // ---- stage 1: global (coalesced float4) -> AL[c][w] bf16 ----
    #pragma unroll
    for (int i = 0; i < 8; ++i) {
        int f = tid + i * 512;            // 0..4095 float4s
        int c = f >> 4;
        int w4 = (f & 15) << 2;
        float4 val = *(const float4*)(aB + (size_t)c * (NH * NW) + w4);
        ushort4 u = { f2bf(val.x), f2bf(val.y), f2bf(val.z), f2bf(val.w) };
        *(ushort4*)(AL + c * 64 + w4) = u;
    }
    __syncthreads();

    // ---- stage 1b: LDS transpose AL[c][w] -> AT[w][c] (swizzled) ----
    {
        int w = tid & 63;
        int cg = tid >> 6;
        #pragma unroll
        for (int it = 0; it < 8; ++it) {
            int c0 = cg * 4 + it * 32;
            ushort4 t;
            t.x = AL[(c0 + 0) * 64 + w];
            t.y = AL[(c0 + 1) * 64 + w];
            t.z = AL[(c0 + 2) * 64 + w];
            t.w = AL[(c0 + 3) * 64 + w];
            *(ushort4*)(AT + idxT(w, c0)) = t;
        }
    }
    __syncthreads();

    const int wv_ = tid >> 6;
    const int lane = tid & 63;
    const int l15 = lane & 15;
    const int g = lane >> 4;

    // ---- stage 2a: QT,KT = (A^T)(W^T)  [M=w:4 tiles, N=o: 32 strips over Q+K] ----
    {
        f32x4 acc[4][4];
        #pragma unroll
        for (int j = 0; j < 4; ++j) {
            int strip = wv_ * 4 + j;
            const float* bias = (strip < 16) ? bq : bk;
            float bvl = bias[((strip & 15) << 4) + l15];
            #pragma unroll
            for (int m = 0; m < 4; ++m)
                acc[j][m] = { bvl, bvl, bvl, bvl };
        }
        const unsigned short* wrow[4];
        #pragma unroll
        for (int j = 0; j < 4; ++j) {
            int strip = wv_ * 4 + j;
            const unsigned short* wb = (strip < 16) ? wsb : (wsb + 65536);
            wrow[j] = wb + (((strip & 15) << 4) + l15) * 256 + g * 8;
        }
        #pragma unroll
        for (int kk = 0; kk < 8; ++kk) {
            bf16x8 af[4], bfr[4];
            #pragma unroll
            for (int m = 0; m < 4; ++m) {
                int w = m * 16 + l15;
                af[m] = *(const bf16x8*)(AT + w * 256 + (((kk * 4 + g) ^ (w & 7)) << 3));
            }
            #pragma unroll
            for (int j = 0; j < 4; ++j)
                bfr[j] = *(const bf16x8*)(wrow[j] + kk * 32);
            #pragma unroll
            for (int j = 0; j < 4; ++j)
                #pragma unroll
                for (int m = 0; m < 4; ++m)
                    acc[j][m] = __builtin_amdgcn_mfma_f32_16x16x32_bf16(af[m], bfr[j], acc[j][m], 0, 0, 0);
        }
        #pragma unroll
        for (int j = 0; j < 4; ++j) {
            int strip = wv_ * 4 + j;
            unsigned short* T = (strip < 16) ? QT : KT;
            int o = ((strip & 15) << 4) + l15;
            #pragma unroll
            for (int m = 0; m < 4; ++m)
                #pragma unroll
                for (int r = 0; r < 4; ++r) {
                    int w = m * 16 + g * 4 + r;
                    T[idxT(w, o)] = f2bf(acc[j][m][r]);
                }
        }
    }

    // ---- stage 2b: Vs = Wv * A   [M=o: 16 tiles, N=x: 4 tiles] ----
    {
        f32x4 acc[2][4];
        #pragma unroll
        for (int mi = 0; mi < 2; ++mi) {
            int m0 = (wv_ * 2 + mi) * 16;
            #pragma unroll
            for (int r = 0; r < 4; ++r) {
                float bvl = bv[m0 + g * 4 + r];
                #pragma unroll
                for (int n = 0; n < 4; ++n) acc[mi][n][r] = bvl;
            }
        }
        #pragma unroll
        for (int kk = 0; kk < 8; ++kk) {
            bf16x8 afw[2], bfa[4];
            #pragma unroll
            for (int mi = 0; mi < 2; ++mi) {
                int m0 = (wv_ * 2 + mi) * 16;
                afw[mi] = *(const bf16x8*)(wsb + 131072 + (m0 + l15) * 256 + kk * 32 + g * 8);
            }
            #pragma unroll
            for (int n = 0; n < 4; ++n) {
                int x = n * 16 + l15;
                bfa[n] = *(const bf16x8*)(AT + x * 256 + (((kk * 4 + g) ^ (x & 7)) << 3));
            }
            #pragma unroll
            for (int mi = 0; mi < 2; ++mi)
                #pragma unroll
                for (int n = 0; n < 4; ++n)
                    acc[mi][n] = __builtin_amdgcn_mfma_f32_16x16x32_bf16(afw[mi], bfa[n], acc[mi][n], 0, 0, 0);
        }
        #pragma unroll
        for (int mi = 0; mi < 2; ++mi)
            #pragma unroll
            for (int n = 0; n < 4; ++n)
                #pragma unroll
                for (int r = 0; r < 4; ++r) {
                    int c = (wv_ * 2 + mi) * 16 + g * 4 + r;
                    int x = n * 16 + l15;
                    Vs[idxS(c, x)] = f2bf(acc[mi][n][r]);
                }
    }
    __syncthreads();

    // ---- stage 3: ATT[w][x] = Q^T K  (K-dim = c = 256) ----
    {
        f32x4 acc[2] = { { 0, 0, 0, 0 }, { 0, 0, 0, 0 } };
        int mt = wv_ >> 1;
        int wr = mt * 16 + l15;
        #pragma unroll
        for (int kk = 0; kk < 8; ++kk) {
            bf16x8 aq = *(const bf16x8*)(QT + wr * 256 + (((kk * 4 + g) ^ (wr & 7)) << 3));
            #pragma unroll
            for (int j = 0; j < 2; ++j) {
                int xr = ((wv_ & 1) * 2 + j) * 16 + l15;
                bf16x8 bkf = *(const bf16x8*)(KT + xr * 256 + (((kk * 4 + g) ^ (xr & 7)) << 3));
                acc[j] = __builtin_amdgcn_mfma_f32_16x16x32_bf16(aq, bkf, acc[j], 0, 0, 0);
            }
        }
        #pragma unroll
        for (int j = 0; j < 2; ++j) {
            int x = ((wv_ & 1) * 2 + j) * 16 + l15;
            #pragma unroll
            for (int r = 0; r < 4; ++r) {
                int w = mt * 16 + g * 4 + r;
                ATT[idxS(w, x)] = f2bf(acc[j][r]);
            }
        }
    }
    __syncthreads();

    // ---- stage 4: O = Vs * ATT^T (K-dim = x = 64), fp32 residual epilogue ----
    {
        f32x4 acc[2][4];
        #pragma unroll
        for (int mi = 0; mi < 2; ++mi)
            #pragma unroll
            for (int n = 0; n < 4; ++n)
                acc[mi][n] = { 0.f, 0.f, 0.f, 0.f };
        #pragma unroll
        for (int kk = 0; kk < 2; ++kk) {
            bf16x8 av[2], bt[4];
            #pragma unroll
            for (int mi = 0; mi < 2; ++mi) {
                int c = (wv_ * 2 + mi) * 16 + l15;
                av[mi] = *(const bf16x8*)(Vs + c * 64 + (((kk * 4 + g) ^ (c & 7)) << 3));
            }
            #pragma unroll
            for (int n = 0; n < 4; ++n) {
                int w = n * 16 + l15;
                bt[n] = *(const bf16x8*)(ATT + w * 64 + (((kk * 4 + g) ^ (w & 7)) << 3));
            }
            #pragma unroll
            for (int mi = 0; mi < 2; ++mi)
                #pragma unroll
                for (int n = 0; n < 4; ++n)
                    acc[mi][n] = __builtin_amdgcn_mfma_f32_16x16x32_bf16(av[mi], bt[n], acc[mi][n], 0, 0, 0);
        }
        #pragma unroll
        for (int mi = 0; mi < 2; ++mi)
            #pragma unroll
            for (int n = 0; n < 4; ++n)
                #pragma unroll
                for (int r = 0; r < 4; ++r) {
                    int c = (wv_ * 2 + mi) * 16 + g * 4 + r;
                    int w = n * 16 + l15;
                    size_t off = (size_t)b * (NC * NH * NW) + (size_t)c * (NH * NW) + h * NW + w;
                    out[off] = a[off] + acc[mi][n][r];
                }
    }
}

extern "C" void kernel_launch(void* const* d_in, const int* in_sizes, int n_in,
                              void* d_out, int out_size, void* d_ws, size_t ws_size,
                              hipStream_t stream) {
    (void)in_sizes; (void)n_in; (void)out_size; (void)ws_size;
    const float* a  = (const float*)d_in[0];
    const float* wq = (const float*)d_in[1];
    const float* bq = (const float*)d_in[2];
    const float* wk = (const float*)d_in[3];
    const float* bk = (const float*)d_in[4];
    const float* wv = (const float*)d_in[5];
    const float* bv = (const float*)d_in[6];
    float* out = (float*)d_out;
    unsigned short* wsb = (unsigned short*)d_ws;  // 3 x 256x256 bf16 weights

    conv_weights<<<dim3(64), dim3(256), 0, stream>>>(wq, wk, wv, wsb);
    mha_fused<<<dim3(NB * NH), dim3(512), 0, stream>>>(a, wsb, bq, bk, bv, out);
}